// Round 2
// baseline (8064.445 us; speedup 1.0000x reference)
//
#include <hip/hip_runtime.h>
#include <math.h>

// Problem constants
#define DIMS   6
#define NGEO   20
#define NPHI   27
#define NEXPERT 540
#define MPTS   256
#define NTEST  1024
#define NMAT   560          // experts + baselines
#define JIT    1e-4f
#define USTRIDE 33280       // packed padded upper-triangular floats per matrix
#define PSW    260          // LDS panel row stride (260 mod 32 = 4 -> bank shift)
#define L2E    1.44269504088896340736f

// Row j of U (cols j..255) starts at uoff(j); each row padded to 4-float multiple.
__device__ __forceinline__ int uoff(int j){
    int m = j >> 2, r = j & 3;
    return 1024*m - 8*m*(m-1) + r*(256 - 4*m);
}

// ---------------------------------------------------------------------------
// Kernel 1: 2-level GMM hard routing (fp64 to match np reference argmax)
// ---------------------------------------------------------------------------
__global__ __launch_bounds__(256)
void route_kernel(const float* __restrict__ Xt, const float* __restrict__ sm,
                  const float* __restrict__ ss,
                  const float* __restrict__ gm, const float* __restrict__ glv,
                  const float* __restrict__ glw,
                  const float* __restrict__ pm, const float* __restrict__ plv,
                  const float* __restrict__ plw,
                  int* __restrict__ e_idx, int* __restrict__ g_idx)
{
    int n = blockIdx.x*256 + threadIdx.x;
    if (n >= NTEST) return;
    double xs[DIMS];
    #pragma unroll
    for (int d=0; d<DIMS; d++)
        xs[d] = ((double)Xt[n*DIMS+d] - (double)sm[d]) / (double)ss[d];
    const double cst = (double)DIMS * 1.8378770664093453;  // D*log(2*pi)

    int bg = 0; double best = -1e300;
    for (int j=0; j<NGEO; j++){
        double s = 0.0;
        #pragma unroll
        for (int d=0; d<DIMS; d++){
            double lv = (double)glv[j*DIMS+d];
            double df = xs[d] - (double)gm[j*DIMS+d];
            s += lv + df*df*exp(-lv);
        }
        double lp = (double)glw[j] - 0.5*(s + cst);
        if (lp > best){ best = lp; bg = j; }
    }
    int bk = 0; best = -1e300;
    for (int k=0; k<NPHI; k++){
        double s = 0.0;
        int o = (bg*NPHI + k)*DIMS;
        #pragma unroll
        for (int d=0; d<DIMS; d++){
            double lv = (double)plv[o+d];
            double df = xs[d] - (double)pm[o+d];
            s += lv + df*df*exp(-lv);
        }
        double lp = (double)plw[bg*NPHI+k] - 0.5*(s + cst);
        if (lp > best){ best = lp; bk = k; }
    }
    e_idx[n] = bg*NPHI + bk;
    g_idx[n] = bg;
}

// ---------------------------------------------------------------------------
// Kernel 2: per-matrix build K, Cholesky (U = L^T packed upper in global ws),
//           and v = L^-1 y.  One block (256 threads) per matrix.
// Panel factor: LDS panel + single-wave shfl diag factor + thread-parallel
// trsm -> 4 barriers/panel (was 32+).
// ---------------------------------------------------------------------------
__global__ __launch_bounds__(256, 3)
void chol_kernel(const float* __restrict__ X_exp, const float* __restrict__ Y_exp,
                 const float* __restrict__ X_base, const float* __restrict__ Y_base,
                 const float* __restrict__ lls_e, const float* __restrict__ los_e,
                 const float* __restrict__ lno_e,
                 const float* __restrict__ lls_b, const float* __restrict__ los_b,
                 const float* __restrict__ lno_b,
                 float* __restrict__ Uws, float* __restrict__ Vws)
{
    __shared__ __align__(16) float Ps[32*PSW];   // panel rows (base-relative cols)
    __shared__ float Dl[32*36];                  // D = diag block of L, row-major
    __shared__ float Dinv[32];                   // 1/diag(L)

    int b = blockIdx.x, t = threadIdx.x;
    const float *Xtr, *Ytr;
    float lls, los, lno;
    if (b < NEXPERT){
        Xtr = X_exp + b*(MPTS*DIMS); Ytr = Y_exp + b*MPTS;
        lls = lls_e[b]; los = los_e[b]; lno = lno_e[b];
    } else {
        int g = b - NEXPERT;
        Xtr = X_base + g*(MPTS*DIMS); Ytr = Y_base + g*MPTS;
        lls = lls_b[g]; los = los_b[g]; lno = lno_b[g];
    }
    float ls2 = expf(2.f*lls);
    float os  = expf(los);
    float nv  = expf(lno) + JIT;
    float c1  = -0.5f*L2E/ls2;
    float* Ug = Uws + (size_t)b*USTRIDE;
    float* Xs = Ps;                    // alias: build phase only (2048 floats)

    // stage X into LDS (padded stride 8; slots 6,7 unused/garbage but never read)
    for (int i=t; i<MPTS*DIMS; i+=256){ int r=i/DIMS, d=i-r*DIMS; Xs[r*8+d]=Xtr[i]; }
    __syncthreads();

    // build K: thread t builds row t of U (cols t..255)
    {
        float x0=Xs[t*8+0], x1=Xs[t*8+1], x2=Xs[t*8+2];
        float x3=Xs[t*8+3], x4=Xs[t*8+4], x5=Xs[t*8+5];
        int ro = uoff(t), len = 256 - t;
        for (int ii=0; ii<len; ii++){
            int i = t + ii;
            float4 a  = *(const float4*)&Xs[i*8];
            float4 b2 = *(const float4*)&Xs[i*8+4];
            float d0=x0-a.x, d1=x1-a.y, d2=x2-a.z, d3=x3-a.w, d4=x4-b2.x, d5=x5-b2.y;
            float dd = d0*d0+d1*d1+d2*d2+d3*d3+d4*d4+d5*d5;
            float u = os*exp2f(c1*dd);
            if (ii==0) u += nv;
            Ug[ro+ii] = u;
        }
        int lp = (len+3)&~3;
        for (int ii=len; ii<lp; ii++) Ug[ro+ii] = 0.f;
    }
    __syncthreads();   // also protects Xs before Ps reuse

    for (int s=0; s<8; s++){
        int base = 32*s;
        int nt = 224 - base;           // trailing size
        // ---- 1. load panel rows (global -> LDS), coalesced per row ----
        #pragma unroll
        for (int c=0; c<32; c++){
            int j = base + c;
            int len = 256 - j;
            if (t < len) Ps[c*PSW + c + t] = Ug[uoff(j) + t];
        }
        __syncthreads();
        // ---- 2. diag 32x32 factor by lanes 0..31 of wave 0 (shfl, no barriers)
        if (t < 32){
            int l = t;
            float r[32];
            #pragma unroll
            for (int k=0; k<32; k++) r[k] = (k <= l) ? Ps[k*PSW + l] : 0.f;
            float myinv = 1.f;
            #pragma unroll
            for (int c=0; c<32; c++){
                float pivsq = __shfl(r[c], c);
                float inv = rsqrtf(pivsq);
                r[c] *= inv;
                if (l == c) myinv = inv;
                #pragma unroll
                for (int k=c+1; k<32; k++) r[k] -= r[c]*__shfl(r[c], k);
            }
            Dinv[l] = myinv;
            #pragma unroll
            for (int j=0; j<32; j++){
                if (j <= l){ Dl[l*36 + j] = r[j]; Ps[j*PSW + l] = r[j]; }
            }
        }
        __syncthreads();
        // ---- 3. trsm: thread-parallel, 2 columns per thread, D via LDS broadcast
        {
            int nt2 = nt >> 1;
            if (t < nt2){
                int it0 = 32 + t, it1 = 32 + nt2 + t;
                float x0[32], x1[32];
                #pragma unroll
                for (int k=0; k<32; k++){
                    x0[k] = Ps[k*PSW + it0];
                    x1[k] = Ps[k*PSW + it1];
                }
                #pragma unroll
                for (int c=0; c<32; c++){
                    float dinv = Dinv[c];
                    float a0 = x0[c]*dinv, a1 = x1[c]*dinv;
                    x0[c] = a0; x1[c] = a1;
                    #pragma unroll
                    for (int k=c+1; k<32; k++){
                        float dkc = Dl[k*36 + c];     // broadcast read
                        x0[k] -= dkc*a0;
                        x1[k] -= dkc*a1;
                    }
                }
                #pragma unroll
                for (int k=0; k<32; k++){
                    Ps[k*PSW + it0] = x0[k];
                    Ps[k*PSW + it1] = x1[k];
                }
            }
        }
        __syncthreads();
        // ---- 4a. write panel back to global (coalesced rows, zero pads) ----
        #pragma unroll
        for (int c=0; c<32; c++){
            int j = base + c;
            int len = 256 - j, lp = (259 - j) & ~3;
            if (t < lp) Ug[uoff(j) + t] = (t < len) ? Ps[c*PSW + c + t] : 0.f;
        }
        // ---- 4b. syrk trailing update: 8x8 register tiles, panel from LDS ----
        {
            int tb = base + 32;
            int ntile = nt >> 3;
            int tri = ntile*(ntile+1)/2;
            for (int tp = t; tp < tri; tp += 256){
                int ti = (int)((sqrtf(8.f*(float)tp + 1.f) - 1.f)*0.5f);
                while ((ti+1)*(ti+2)/2 <= tp) ti++;
                while (ti*(ti+1)/2 > tp) ti--;
                int tj = tp - ti*(ti+1)/2;
                int I0 = tb + ti*8, K0 = tb + tj*8;
                float acc[8][8];
                int roK[8];
                #pragma unroll
                for (int kk=0; kk<8; kk++) roK[kk] = uoff(K0+kk);
                #pragma unroll
                for (int kk=0; kk<8; kk++){
                    int kr = K0+kk;
                    #pragma unroll
                    for (int ii=0; ii<8; ii++){
                        int ic = I0+ii;
                        acc[kk][ii] = (ic >= kr) ? Ug[roK[kk] + ic - kr] : 0.f;
                    }
                }
                int i0r = I0 - base, k0r = K0 - base;
                #pragma unroll
                for (int c=0; c<32; c++){
                    float4 a0 = *(const float4*)&Ps[c*PSW + i0r];
                    float4 a1 = *(const float4*)&Ps[c*PSW + i0r + 4];
                    float4 b0 = *(const float4*)&Ps[c*PSW + k0r];
                    float4 b1 = *(const float4*)&Ps[c*PSW + k0r + 4];
                    float av[8] = {a0.x,a0.y,a0.z,a0.w,a1.x,a1.y,a1.z,a1.w};
                    float bv[8] = {b0.x,b0.y,b0.z,b0.w,b1.x,b1.y,b1.z,b1.w};
                    #pragma unroll
                    for (int kk=0; kk<8; kk++)
                        #pragma unroll
                        for (int ii=0; ii<8; ii++)
                            acc[kk][ii] -= bv[kk]*av[ii];
                }
                #pragma unroll
                for (int kk=0; kk<8; kk++){
                    int kr = K0+kk;
                    #pragma unroll
                    for (int ii=0; ii<8; ii++){
                        int ic = I0+ii;
                        if (ic >= kr) Ug[roK[kk] + ic - kr] = acc[kk][ii];
                    }
                }
            }
        }
        __syncthreads();
    }

    // v = L^-1 y  (forward solve, wave 0 only; L columns = U rows, coalesced)
    if (t < 64){
        int l = t;
        float z[4], rd[4];
        #pragma unroll
        for (int q=0; q<4; q++){
            z[q]  = Ytr[64*q + l];
            rd[q] = 1.f/Ug[uoff(64*q + l)];
        }
        int offj = 0;
        #pragma unroll
        for (int q=0; q<4; q++){
            for (int j2=0; j2<64; j2++){
                int j = 64*q + j2;
                float zf = __shfl(z[q], j2) * __shfl(rd[q], j2);
                if (l == j2) z[q] = zf;
                #pragma unroll
                for (int r=q; r<4; r++){
                    int dd = 64*(r-q) + (l - j2);
                    int dc = dd > 0 ? dd : 0;
                    float uv = Ug[offj + dc];
                    if (dd > 0) z[r] -= uv*zf;
                }
                offj += (259-j)&~3;
            }
        }
        #pragma unroll
        for (int q=0; q<4; q++) Vws[b*256 + 64*q + l] = z[q];
    }
}

// ---------------------------------------------------------------------------
// Kernel 3: per-point prediction (one wave per (point, side)) + rBCM combine
// ---------------------------------------------------------------------------
__global__ __launch_bounds__(256)
void predict_kernel(const float* __restrict__ Xt,
                    const float* __restrict__ X_exp, const float* __restrict__ X_base,
                    const float* __restrict__ lls_e, const float* __restrict__ los_e,
                    const float* __restrict__ lno_e,
                    const float* __restrict__ lls_b, const float* __restrict__ los_b,
                    const float* __restrict__ lno_b,
                    const int* __restrict__ nullmask,
                    const float* __restrict__ Uws, const float* __restrict__ Vws,
                    const int* __restrict__ e_idx, const int* __restrict__ g_idx,
                    float* __restrict__ out)
{
    __shared__ float res[4][4];   // per local wave: mu, var, prior
    int lw = threadIdx.x >> 6, l = threadIdx.x & 63;
    int wt = blockIdx.x*4 + lw, n = wt >> 1, side = wt & 1;

    int bidx; const float* Xtr; float lls, los, lno;
    if (side == 0){
        int ee = e_idx[n]; bidx = ee; Xtr = X_exp + ee*(MPTS*DIMS);
        lls = lls_e[ee]; los = los_e[ee]; lno = lno_e[ee];
    } else {
        int g = g_idx[n]; bidx = NEXPERT + g; Xtr = X_base + g*(MPTS*DIMS);
        lls = lls_b[g]; los = los_b[g]; lno = lno_b[g];
    }
    float ls2 = expf(2.f*lls), os = expf(los), nv = expf(lno) + JIT;
    float c1 = -0.5f*L2E/ls2;
    float xt[DIMS];
    #pragma unroll
    for (int d=0; d<DIMS; d++) xt[d] = Xt[n*DIMS + d];

    const float* Ug = Uws + (size_t)bidx*USTRIDE;
    const float* vv = Vws + bidx*256;

    // k* into registers (rows 64q+l), plus diag reciprocals
    float z[4], rd[4];
    #pragma unroll
    for (int q=0; q<4; q++){
        int m = 64*q + l;
        float d2 = 0.f;
        #pragma unroll
        for (int d=0; d<DIMS; d++){ float df = xt[d]-Xtr[m*DIMS+d]; d2 += df*df; }
        z[q]  = os*exp2f(c1*d2);
        rd[q] = 1.f/Ug[uoff(m)];
    }
    // w = L^-1 k*  (forward solve; L columns = U rows, coalesced loads)
    int offj = 0;
    #pragma unroll
    for (int q=0; q<4; q++){
        #pragma unroll 4
        for (int j2=0; j2<64; j2++){
            int j = 64*q + j2;
            float zf = __shfl(z[q], j2) * __shfl(rd[q], j2);
            if (l == j2) z[q] = zf;
            #pragma unroll
            for (int r=q; r<4; r++){
                int dd = 64*(r-q) + (l - j2);
                int dc = dd > 0 ? dd : 0;
                float uv = Ug[offj + dc];
                if (dd > 0) z[r] -= uv*zf;
            }
            offj += (259-j)&~3;
        }
    }
    // q = w.w ; mu = w.v
    float qq = 0.f, mu = 0.f;
    #pragma unroll
    for (int q=0; q<4; q++){ qq += z[q]*z[q]; mu += z[q]*vv[64*q + l]; }
    #pragma unroll
    for (int o=32; o>0; o>>=1){ qq += __shfl_xor(qq, o); mu += __shfl_xor(mu, o); }
    if (l == 0){
        res[lw][0] = mu;
        res[lw][1] = fmaxf(os - qq, JIT) + nv;   // predictive var incl noise
        res[lw][2] = os + nv;                    // prior
    }
    __syncthreads();
    if (threadIdx.x < 2){
        int pp = threadIdx.x, n2 = blockIdx.x*2 + pp;
        float mu_e = res[2*pp][0],   var_e = res[2*pp][1],   pr_e = res[2*pp][2];
        float mu_b = res[2*pp+1][0], var_b = res[2*pp+1][1], pr_b = res[2*pp+1][2];
        int ee = e_idx[n2];
        float be = (nullmask[ee] == 0) ? 0.f
                 : fmaxf(0.5f*(logf(pr_e) - logf(var_e)), 0.f);
        float bb = fmaxf(0.5f*(logf(pr_b) - logf(var_b)), 0.f);
        float prec = be/var_e + bb/var_b + (1.f - be - bb)/pr_b;
        prec = fmaxf(prec, 1e-6f);
        out[n2]        = (be*mu_e/var_e + bb*mu_b/var_b)/prec;
        out[NTEST + n2] = 1.f/prec;
    }
}

// ---------------------------------------------------------------------------
extern "C" void kernel_launch(void* const* d_in, const int* in_sizes, int n_in,
                              void* d_out, int out_size, void* d_ws, size_t ws_size,
                              hipStream_t stream)
{
    const float* X_test  = (const float*)d_in[0];
    const float* X_exp   = (const float*)d_in[1];
    const float* Y_exp   = (const float*)d_in[2];
    const float* X_base  = (const float*)d_in[3];
    const float* Y_base  = (const float*)d_in[4];
    const float* lls_e   = (const float*)d_in[5];
    const float* los_e   = (const float*)d_in[6];
    const float* lno_e   = (const float*)d_in[7];
    const float* lls_b   = (const float*)d_in[8];
    const float* los_b   = (const float*)d_in[9];
    const float* lno_b   = (const float*)d_in[10];
    const float* sm      = (const float*)d_in[11];
    const float* ss      = (const float*)d_in[12];
    const float* gm      = (const float*)d_in[13];
    const float* glv     = (const float*)d_in[14];
    const float* glw     = (const float*)d_in[15];
    const float* pm      = (const float*)d_in[16];
    const float* plv     = (const float*)d_in[17];
    const float* plw     = (const float*)d_in[18];
    const int*   nmask   = (const int*)d_in[19];

    float* Uws = (float*)d_ws;                       // NMAT*USTRIDE floats (74.5 MB)
    float* Vws = Uws + (size_t)NMAT*USTRIDE;         // NMAT*256 floats
    int*   e_idx = (int*)(Vws + (size_t)NMAT*256);   // NTEST ints
    int*   g_idx = e_idx + NTEST;                    // NTEST ints
    float* out = (float*)d_out;

    route_kernel<<<dim3(NTEST/256), dim3(256), 0, stream>>>(
        X_test, sm, ss, gm, glv, glw, pm, plv, plw, e_idx, g_idx);
    chol_kernel<<<dim3(NMAT), dim3(256), 0, stream>>>(
        X_exp, Y_exp, X_base, Y_base,
        lls_e, los_e, lno_e, lls_b, los_b, lno_b, Uws, Vws);
    predict_kernel<<<dim3(NTEST/2), dim3(256), 0, stream>>>(
        X_test, X_exp, X_base,
        lls_e, los_e, lno_e, lls_b, los_b, lno_b,
        nmask, Uws, Vws, e_idx, g_idx, out);
}

// Round 3
// 582.780 us; speedup vs baseline: 13.8379x; 13.8379x over previous
//
#include <hip/hip_runtime.h>
#include <math.h>

// Problem constants
#define DIMS   6
#define NGEO   20
#define NPHI   27
#define NEXPERT 540
#define MPTS   256
#define NTEST  1024
#define NMAT   560          // experts + baselines
#define JIT    1e-4f
#define USTRIDE 33280       // packed padded upper-triangular floats per matrix
#define L2E    1.44269504088896340736f

// Row j of U (cols j..255) starts at uoff(j); each row padded to 4-float multiple.
__device__ __forceinline__ int uoff(int j){
    int m = j >> 2, r = j & 3;
    return 1024*m - 8*m*(m-1) + r*(256 - 4*m);
}

// ---------------------------------------------------------------------------
// Kernel 1: 2-level GMM hard routing (fp64 to match np reference argmax)
// ---------------------------------------------------------------------------
__global__ __launch_bounds__(256)
void route_kernel(const float* __restrict__ Xt, const float* __restrict__ sm,
                  const float* __restrict__ ss,
                  const float* __restrict__ gm, const float* __restrict__ glv,
                  const float* __restrict__ glw,
                  const float* __restrict__ pm, const float* __restrict__ plv,
                  const float* __restrict__ plw,
                  int* __restrict__ e_idx, int* __restrict__ g_idx)
{
    int n = blockIdx.x*256 + threadIdx.x;
    if (n >= NTEST) return;
    double xs[DIMS];
    #pragma unroll
    for (int d=0; d<DIMS; d++)
        xs[d] = ((double)Xt[n*DIMS+d] - (double)sm[d]) / (double)ss[d];
    const double cst = (double)DIMS * 1.8378770664093453;  // D*log(2*pi)

    int bg = 0; double best = -1e300;
    for (int j=0; j<NGEO; j++){
        double s = 0.0;
        #pragma unroll
        for (int d=0; d<DIMS; d++){
            double lv = (double)glv[j*DIMS+d];
            double df = xs[d] - (double)gm[j*DIMS+d];
            s += lv + df*df*exp(-lv);
        }
        double lp = (double)glw[j] - 0.5*(s + cst);
        if (lp > best){ best = lp; bg = j; }
    }
    int bk = 0; best = -1e300;
    for (int k=0; k<NPHI; k++){
        double s = 0.0;
        int o = (bg*NPHI + k)*DIMS;
        #pragma unroll
        for (int d=0; d<DIMS; d++){
            double lv = (double)plv[o+d];
            double df = xs[d] - (double)pm[o+d];
            s += lv + df*df*exp(-lv);
        }
        double lp = (double)plw[bg*NPHI+k] - 0.5*(s + cst);
        if (lp > best){ best = lp; bk = k; }
    }
    e_idx[n] = bg*NPHI + bk;
    g_idx[n] = bg;
}

// ---------------------------------------------------------------------------
// Kernel 2: left-looking Cholesky, panel columns resident in registers.
// Thread t owns column u=(t+64j)&255 of panel j (32 floats in VGPRs):
//   build-K (RBF from X in LDS) -> subtract prev panels (staged via LDS,
//   read once each) -> shfl diag factor -> in-thread trsm -> store once.
// Global traffic: write triangle once + stream prev panels (~0.5 MB/matrix)
// vs R2's 35 MB/matrix trailing-matrix churn.
// ---------------------------------------------------------------------------
__global__ __launch_bounds__(256, 3)
void chol_kernel(const float* __restrict__ X_exp, const float* __restrict__ Y_exp,
                 const float* __restrict__ X_base, const float* __restrict__ Y_base,
                 const float* __restrict__ lls_e, const float* __restrict__ los_e,
                 const float* __restrict__ lno_e,
                 const float* __restrict__ lls_b, const float* __restrict__ los_b,
                 const float* __restrict__ lno_b,
                 float* __restrict__ Uws, float* __restrict__ Vws)
{
    __shared__ __align__(16) float Xs[256*8];    // 8 KB   train points, stride 8
    __shared__ __align__(16) float S[32*228];    // 29.2 KB staged prev panel
    __shared__ float Dl[32*36];                  // 4.6 KB  diag block of L
    __shared__ float Dinv[32];                   // 1/diag(L)

    int b = blockIdx.x, t = threadIdx.x;
    const float *Xtr, *Ytr;
    float lls, los, lno;
    if (b < NEXPERT){
        Xtr = X_exp + b*(MPTS*DIMS); Ytr = Y_exp + b*MPTS;
        lls = lls_e[b]; los = los_e[b]; lno = lno_e[b];
    } else {
        int g = b - NEXPERT;
        Xtr = X_base + g*(MPTS*DIMS); Ytr = Y_base + g*MPTS;
        lls = lls_b[g]; los = los_b[g]; lno = lno_b[g];
    }
    float ls2 = expf(2.f*lls);
    float os  = expf(los);
    float nv  = expf(lno) + JIT;
    float c1  = -0.5f*L2E/ls2;
    float* Ug = Uws + (size_t)b*USTRIDE;

    // stage X into LDS (padded stride 8; slots 6,7 never read)
    for (int i=t; i<MPTS*DIMS; i+=256){ int r=i/DIMS, d=i-r*DIMS; Xs[r*8+d]=Xtr[i]; }
    __syncthreads();

    for (int j=0; j<8; j++){
        int len = 256 - 32*j;
        int u = (t + ((j & 3) << 6)) & 255;   // rotated column -> wave balance
        bool active = (u < len);
        int c = 32*j + u;                      // absolute column
        float x[32];                           // x[k] = U[32j+k][c]

        // ---- build original K entries for this column ----
        if (active){
            float4 xa = *(const float4*)&Xs[c*8];
            float2 xb = *(const float2*)&Xs[c*8+4];
            #pragma unroll
            for (int k=0; k<32; k++){
                const float* Xr = &Xs[(32*j+k)*8];
                float4 ra = *(const float4*)Xr;
                float2 rb = *(const float2*)(Xr+4);
                float d0=xa.x-ra.x, d1=xa.y-ra.y, d2v=xa.z-ra.z, d3=xa.w-ra.w;
                float d4=xb.x-rb.x, d5=xb.y-rb.y;
                float dd = d0*d0+d1*d1+d2v*d2v+d3*d3+d4*d4+d5*d5;
                float val = os*exp2f(c1*dd);
                if (k == u) val += nv;         // diagonal
                x[k] = val;
            }
        }

        // ---- subtract contributions of previous panels (left-looking) ----
        for (int i2=0; i2<j; i2++){
            __syncthreads();                   // S free for reuse
            if (t < len){
                #pragma unroll
                for (int m=0; m<32; m++){
                    int ri = 32*i2 + m;
                    S[m*228 + t] = Ug[uoff(ri) + 32*j + t - ri];
                }
            }
            __syncthreads();
            if (active){
                #pragma unroll 4
                for (int m=0; m<32; m++){
                    float a = S[m*228 + u];    // U[ri][c]
                    const float4* Sr = (const float4*)&S[m*228];
                    #pragma unroll
                    for (int kk=0; kk<8; kk++){
                        float4 bb = Sr[kk];    // U[ri][32j+4kk..] broadcast
                        x[kk*4+0] -= bb.x*a;
                        x[kk*4+1] -= bb.y*a;
                        x[kk*4+2] -= bb.z*a;
                        x[kk*4+3] -= bb.w*a;
                    }
                }
            }
        }

        // ---- diag 32x32 factor: lanes t0..t0+31 (u=0..31), shfl only ----
        int t0 = (256 - ((j & 3) << 6)) & 255; // lane block holding u<32
        if (t >= t0 && t < t0 + 32){
            int l = t - t0;                    // == u
            float r[32];
            #pragma unroll
            for (int k=0; k<32; k++) r[k] = (k <= l) ? x[k] : 0.f;
            float myinv = 1.f;
            #pragma unroll
            for (int cc=0; cc<32; cc++){
                float pivsq = __shfl(r[cc], cc);
                float inv = rsqrtf(pivsq);
                r[cc] *= inv;
                if (l == cc) myinv = inv;
                #pragma unroll
                for (int k=cc+1; k<32; k++) r[k] -= r[cc]*__shfl(r[cc], k);
            }
            Dinv[l] = myinv;
            #pragma unroll
            for (int k=0; k<32; k++){
                if (k <= l) Dl[l*36 + k] = r[k];
                x[k] = r[k];
            }
        }
        __syncthreads();

        // ---- trsm: in-thread, D via LDS broadcast ----
        if (active && u >= 32){
            #pragma unroll
            for (int cc=0; cc<32; cc++){
                float a = x[cc]*Dinv[cc];
                x[cc] = a;
                #pragma unroll
                for (int k=cc+1; k<32; k++)
                    x[k] -= Dl[k*36 + cc]*a;
            }
        }

        // ---- store panel column to global (once) ----
        if (active){
            #pragma unroll
            for (int k=0; k<32; k++){
                if (u >= k) Ug[uoff(32*j+k) + u - k] = x[k];
            }
        }
    }
    __syncthreads();

    // v = L^-1 y  (forward solve, wave 0 only; L columns = U rows, coalesced)
    if (t < 64){
        int l = t;
        float z[4], rd[4];
        #pragma unroll
        for (int q=0; q<4; q++){
            z[q]  = Ytr[64*q + l];
            rd[q] = 1.f/Ug[uoff(64*q + l)];
        }
        int offj = 0;
        #pragma unroll
        for (int q=0; q<4; q++){
            for (int j2=0; j2<64; j2++){
                int j = 64*q + j2;
                float zf = __shfl(z[q], j2) * __shfl(rd[q], j2);
                if (l == j2) z[q] = zf;
                #pragma unroll
                for (int r=q; r<4; r++){
                    int dd = 64*(r-q) + (l - j2);
                    int dc = dd > 0 ? dd : 0;
                    float uv = Ug[offj + dc];
                    if (dd > 0) z[r] -= uv*zf;
                }
                offj += (259-j)&~3;
            }
        }
        #pragma unroll
        for (int q=0; q<4; q++) Vws[b*256 + 64*q + l] = z[q];
    }
}

// ---------------------------------------------------------------------------
// Kernel 3: per-point prediction (one wave per (point, side)) + rBCM combine
// ---------------------------------------------------------------------------
__global__ __launch_bounds__(256)
void predict_kernel(const float* __restrict__ Xt,
                    const float* __restrict__ X_exp, const float* __restrict__ X_base,
                    const float* __restrict__ lls_e, const float* __restrict__ los_e,
                    const float* __restrict__ lno_e,
                    const float* __restrict__ lls_b, const float* __restrict__ los_b,
                    const float* __restrict__ lno_b,
                    const int* __restrict__ nullmask,
                    const float* __restrict__ Uws, const float* __restrict__ Vws,
                    const int* __restrict__ e_idx, const int* __restrict__ g_idx,
                    float* __restrict__ out)
{
    __shared__ float res[4][4];   // per local wave: mu, var, prior
    int lw = threadIdx.x >> 6, l = threadIdx.x & 63;
    int wt = blockIdx.x*4 + lw, n = wt >> 1, side = wt & 1;

    int bidx; const float* Xtr; float lls, los, lno;
    if (side == 0){
        int ee = e_idx[n]; bidx = ee; Xtr = X_exp + ee*(MPTS*DIMS);
        lls = lls_e[ee]; los = los_e[ee]; lno = lno_e[ee];
    } else {
        int g = g_idx[n]; bidx = NEXPERT + g; Xtr = X_base + g*(MPTS*DIMS);
        lls = lls_b[g]; los = los_b[g]; lno = lno_b[g];
    }
    float ls2 = expf(2.f*lls), os = expf(los), nv = expf(lno) + JIT;
    float c1 = -0.5f*L2E/ls2;
    float xt[DIMS];
    #pragma unroll
    for (int d=0; d<DIMS; d++) xt[d] = Xt[n*DIMS + d];

    const float* Ug = Uws + (size_t)bidx*USTRIDE;
    const float* vv = Vws + bidx*256;

    // k* into registers (rows 64q+l), plus diag reciprocals
    float z[4], rd[4];
    #pragma unroll
    for (int q=0; q<4; q++){
        int m = 64*q + l;
        float d2 = 0.f;
        #pragma unroll
        for (int d=0; d<DIMS; d++){ float df = xt[d]-Xtr[m*DIMS+d]; d2 += df*df; }
        z[q]  = os*exp2f(c1*d2);
        rd[q] = 1.f/Ug[uoff(m)];
    }
    // w = L^-1 k*  (forward solve; L columns = U rows, coalesced loads)
    int offj = 0;
    #pragma unroll
    for (int q=0; q<4; q++){
        #pragma unroll 4
        for (int j2=0; j2<64; j2++){
            int j = 64*q + j2;
            float zf = __shfl(z[q], j2) * __shfl(rd[q], j2);
            if (l == j2) z[q] = zf;
            #pragma unroll
            for (int r=q; r<4; r++){
                int dd = 64*(r-q) + (l - j2);
                int dc = dd > 0 ? dd : 0;
                float uv = Ug[offj + dc];
                if (dd > 0) z[r] -= uv*zf;
            }
            offj += (259-j)&~3;
        }
    }
    // q = w.w ; mu = w.v
    float qq = 0.f, mu = 0.f;
    #pragma unroll
    for (int q=0; q<4; q++){ qq += z[q]*z[q]; mu += z[q]*vv[64*q + l]; }
    #pragma unroll
    for (int o=32; o>0; o>>=1){ qq += __shfl_xor(qq, o); mu += __shfl_xor(mu, o); }
    if (l == 0){
        res[lw][0] = mu;
        res[lw][1] = fmaxf(os - qq, JIT) + nv;   // predictive var incl noise
        res[lw][2] = os + nv;                    // prior
    }
    __syncthreads();
    if (threadIdx.x < 2){
        int pp = threadIdx.x, n2 = blockIdx.x*2 + pp;
        float mu_e = res[2*pp][0],   var_e = res[2*pp][1],   pr_e = res[2*pp][2];
        float mu_b = res[2*pp+1][0], var_b = res[2*pp+1][1], pr_b = res[2*pp+1][2];
        int ee = e_idx[n2];
        float be = (nullmask[ee] == 0) ? 0.f
                 : fmaxf(0.5f*(logf(pr_e) - logf(var_e)), 0.f);
        float bb = fmaxf(0.5f*(logf(pr_b) - logf(var_b)), 0.f);
        float prec = be/var_e + bb/var_b + (1.f - be - bb)/pr_b;
        prec = fmaxf(prec, 1e-6f);
        out[n2]        = (be*mu_e/var_e + bb*mu_b/var_b)/prec;
        out[NTEST + n2] = 1.f/prec;
    }
}

// ---------------------------------------------------------------------------
extern "C" void kernel_launch(void* const* d_in, const int* in_sizes, int n_in,
                              void* d_out, int out_size, void* d_ws, size_t ws_size,
                              hipStream_t stream)
{
    const float* X_test  = (const float*)d_in[0];
    const float* X_exp   = (const float*)d_in[1];
    const float* Y_exp   = (const float*)d_in[2];
    const float* X_base  = (const float*)d_in[3];
    const float* Y_base  = (const float*)d_in[4];
    const float* lls_e   = (const float*)d_in[5];
    const float* los_e   = (const float*)d_in[6];
    const float* lno_e   = (const float*)d_in[7];
    const float* lls_b   = (const float*)d_in[8];
    const float* los_b   = (const float*)d_in[9];
    const float* lno_b   = (const float*)d_in[10];
    const float* sm      = (const float*)d_in[11];
    const float* ss      = (const float*)d_in[12];
    const float* gm      = (const float*)d_in[13];
    const float* glv     = (const float*)d_in[14];
    const float* glw     = (const float*)d_in[15];
    const float* pm      = (const float*)d_in[16];
    const float* plv     = (const float*)d_in[17];
    const float* plw     = (const float*)d_in[18];
    const int*   nmask   = (const int*)d_in[19];

    float* Uws = (float*)d_ws;                       // NMAT*USTRIDE floats (74.5 MB)
    float* Vws = Uws + (size_t)NMAT*USTRIDE;         // NMAT*256 floats
    int*   e_idx = (int*)(Vws + (size_t)NMAT*256);   // NTEST ints
    int*   g_idx = e_idx + NTEST;                    // NTEST ints
    float* out = (float*)d_out;

    route_kernel<<<dim3(NTEST/256), dim3(256), 0, stream>>>(
        X_test, sm, ss, gm, glv, glw, pm, plv, plw, e_idx, g_idx);
    chol_kernel<<<dim3(NMAT), dim3(256), 0, stream>>>(
        X_exp, Y_exp, X_base, Y_base,
        lls_e, los_e, lno_e, lls_b, los_b, lno_b, Uws, Vws);
    predict_kernel<<<dim3(NTEST/2), dim3(256), 0, stream>>>(
        X_test, X_exp, X_base,
        lls_e, los_e, lno_e, lls_b, los_b, lno_b,
        nmask, Uws, Vws, e_idx, g_idx, out);
}